// Round 7
// baseline (891.337 us; speedup 1.0000x reference)
//
#include <hip/hip_runtime.h>

#define TT 512

typedef _Float16 f16;
typedef _Float16 f16x8 __attribute__((ext_vector_type(8)));
typedef float f32x4 __attribute__((ext_vector_type(4)));

__device__ __forceinline__ float fsig(float x){
    return __builtin_amdgcn_rcpf(1.f + __expf(-x));
}
__device__ __forceinline__ float ftanh_(float x){
    return 2.f * __builtin_amdgcn_rcpf(1.f + __expf(-2.f*x)) - 1.f;
}

// Wp (f16): [14 m][2 kt][64 lane][8 b] A-fragments for mfma_f32_16x16x32_f16
//   packed row r = m*16 + (lane&15), r = 4*u+g (unit-major); k = kt*32 + (lane>>4)*8 + b
//   zero-padded for u>=51 (rows) and k>=51 (cols)
// Wp2 (f32): [56 u][4 g] = Wih2[g*51+u], zero-padded
__global__ void repack_w(const float* __restrict__ Whh1, const float* __restrict__ Wih2,
                         f16* __restrict__ Wp, float* __restrict__ Wp2)
{
    int i = blockIdx.x*256 + threadIdx.x;
    if (i < 14*2*64*8) {
        int b    = i & 7;
        int lane = (i >> 3) & 63;
        int kt   = (i >> 9) & 1;
        int m    = i >> 10;
        int r = m*16 + (lane & 15);
        int u = r >> 2, g = r & 3;
        int k = kt*32 + (lane >> 4)*8 + b;
        float v = (u < 51 && k < 51) ? Whh1[(g*51+u)*51 + k] : 0.f;
        Wp[i] = (f16)v;
    }
    if (i < 224) {
        int u = i >> 2, g = i & 3;
        Wp2[i] = (u < 51) ? Wih2[g*51 + u] : 0.f;
    }
}

// HB bytes: parity*2048 + jl*128 + swz(group,jl)*16 + elem*2, group = unit>>3, swz = group^(jl&7)
// PBL bytes: parity*512 + wave*256 + jl*16  (f32x4 gate partials)
__device__ __forceinline__ void lstm1_phase(
    int rp, float xin, bool writeH,
    const f16x8 (&A0)[7], const f16x8 (&A1)[7],
    const float (&bs)[7][4], const float (&wi)[7][4],
    const f32x4 (&w2q)[7],
    float (&c1)[7],
    char* hb, char* pbl, int jl, int q, int wv, int lane)
{
    const char* rbase = hb + rp*2048 + jl*128;
    const int d = jl & 7;
    f16x8 B0 = *(const f16x8*)(rbase + ((q^d)<<4));
    f16x8 B1 = *(const f16x8*)(rbase + (((4+q)^d)<<4));

    f32x4 acc[7];
    #pragma unroll
    for (int j = 0; j < 7; ++j) {
        #pragma unroll
        for (int g = 0; g < 4; ++g) acc[j][g] = bs[j][g] + wi[j][g]*xin;
    }
    #pragma unroll
    for (int j = 0; j < 7; ++j) acc[j] = __builtin_amdgcn_mfma_f32_16x16x32_f16(A0[j], B0, acc[j], 0,0,0);
    #pragma unroll
    for (int j = 0; j < 7; ++j) acc[j] = __builtin_amdgcn_mfma_f32_16x16x32_f16(A1[j], B1, acc[j], 0,0,0);

    char* wbase = hb + (rp^1)*2048 + jl*128;
    f32x4 p; p[0]=p[1]=p[2]=p[3]=0.f;
    #pragma unroll
    for (int j = 0; j < 7; ++j) {
        float ig = fsig(acc[j][0]), fg = fsig(acc[j][1]), gg = ftanh_(acc[j][2]);
        float c = fg*c1[j] + ig*gg;
        c1[j] = c;
        if (writeH) {
            float og = fsig(acc[j][3]);
            float hv = og * ftanh_(c);
            int u = (wv*7 + j)*4 + q;
            *(f16*)(wbase + (((u>>3)^d)<<4) + ((u&7)<<1)) = (f16)hv;
        }
        #pragma unroll
        for (int g = 0; g < 4; ++g) p[g] += w2q[j][g]*c;
    }
    #pragma unroll
    for (int g = 0; g < 4; ++g) { p[g] += __shfl_xor(p[g], 16); p[g] += __shfl_xor(p[g], 32); }
    if (lane < 16)
        *(f32x4*)(pbl + (rp^1)*512 + wv*256 + jl*16) = p;
}

__device__ __forceinline__ void lstm2_phase(
    int rp, const char* pbl, int jl,
    const float (&bs2)[4], const float (&wh2)[4], float& h2, float& c2, bool needO)
{
    f32x4 P0 = *(const f32x4*)(pbl + (rp^1)*512 +       jl*16);
    f32x4 P1 = *(const f32x4*)(pbl + (rp^1)*512 + 256 + jl*16);
    float g0 = P0[0] + P1[0] + bs2[0] + wh2[0]*h2;
    float g1 = P0[1] + P1[1] + bs2[1] + wh2[1]*h2;
    float g2 = P0[2] + P1[2] + bs2[2] + wh2[2]*h2;
    float i2 = fsig(g0), f2 = fsig(g1), gg2 = ftanh_(g2);
    c2 = f2*c2 + i2*gg2;
    if (needO) {
        float g3 = P0[3] + P1[3] + bs2[3] + wh2[3]*h2;
        float o2 = fsig(g3);
        h2 = o2*ftanh_(c2);
    }
}

__global__ __launch_bounds__(128, 1) void lstm_main(
    const float* __restrict__ X, const f16* __restrict__ Wp, const float* __restrict__ Wp2,
    const float* __restrict__ Wih1, const float* __restrict__ bih1, const float* __restrict__ bhh1,
    const float* __restrict__ Whh2, const float* __restrict__ bih2, const float* __restrict__ bhh2,
    float* __restrict__ out)
{
    __shared__ __align__(16) char HBs[4096];   // h, 2 parities x 16 batch x 64 units f16 (swizzled)
    __shared__ __align__(16) char PBL[1024];   // layer-2 partials, 2 parities x 2 waves x 16 x f32x4

    const int tid  = threadIdx.x;
    const int wv   = tid >> 6;       // wave 0/1: M-tiles wv*7 .. wv*7+6
    const int lane = tid & 63;
    const int q    = lane >> 4;
    const int jl   = lane & 15;      // batch within block
    const int bb   = blockIdx.x * 16;

    for (int i = tid; i < 1024; i += 128) ((unsigned*)HBs)[i] = 0u;  // zero both parities (pads must stay 0)

    f16x8 A0[7], A1[7];
    float bs[7][4], wi[7][4];
    f32x4 w2q[7];
    #pragma unroll
    for (int j = 0; j < 7; ++j) {
        int m = wv*7 + j;
        A0[j] = *(const f16x8*)(Wp + (m*2+0)*512 + lane*8);
        A1[j] = *(const f16x8*)(Wp + (m*2+1)*512 + lane*8);
        int u = m*4 + q;
        #pragma unroll
        for (int g = 0; g < 4; ++g) {
            if (u < 51) { int rt = g*51 + u; bs[j][g] = bih1[rt] + bhh1[rt]; wi[j][g] = Wih1[rt]; }
            else        { bs[j][g] = 0.f; wi[j][g] = 0.f; }
        }
        w2q[j] = *(const f32x4*)(Wp2 + u*4);
    }
    float wh2[4], bs2[4];
    #pragma unroll
    for (int g = 0; g < 4; ++g) { wh2[g] = Whh2[g]; bs2[g] = bih2[g] + bhh2[g]; }

    float c1[7];
    #pragma unroll
    for (int j = 0; j < 7; ++j) c1[j] = 0.f;
    float h2 = 0.f, c2 = 0.f;

    __syncthreads();

    const float* xp = X + (size_t)(bb + jl) * TT;
    float xc = xp[0];

    for (int t = 0; t < TT; t += 2) {
        float xn1 = xp[t+1];
        lstm1_phase(0, xc, true, A0, A1, bs, wi, w2q, c1, HBs, PBL, jl, q, wv, lane);
        __syncthreads();
        float xn2 = (t+2 < TT) ? xp[t+2] : 0.f;
        lstm2_phase(0, PBL, jl, bs2, wh2, h2, c2, true);

        lstm1_phase(1, xn1, true, A0, A1, bs, wi, w2q, c1, HBs, PBL, jl, q, wv, lane);
        __syncthreads();
        lstm2_phase(1, PBL, jl, bs2, wh2, h2, c2, true);

        xc = xn2;
    }
    // h(511) is in parity 0; c2/h2 are through step 511 (all lanes hold them)

    // extra step: lstm1(input = c2) -> c1'; lstm2(input = c1') -> out = new c2
    lstm1_phase(0, c2, false, A0, A1, bs, wi, w2q, c1, HBs, PBL, jl, q, wv, lane);
    __syncthreads();
    lstm2_phase(0, PBL, jl, bs2, wh2, h2, c2, false);

    if (tid < 16) out[bb + jl] = c2;
}

extern "C" void kernel_launch(void* const* d_in, const int* in_sizes, int n_in,
                              void* d_out, int out_size, void* d_ws, size_t ws_size,
                              hipStream_t stream) {
    const float* X    = (const float*)d_in[0];
    const float* Wih1 = (const float*)d_in[1];
    const float* Whh1 = (const float*)d_in[2];
    const float* bih1 = (const float*)d_in[3];
    const float* bhh1 = (const float*)d_in[4];
    const float* Wih2 = (const float*)d_in[5];
    const float* Whh2 = (const float*)d_in[6];
    const float* bih2 = (const float*)d_in[7];
    const float* bhh2 = (const float*)d_in[8];
    float* out = (float*)d_out;

    f16*   Wp  = (f16*)d_ws;                      // 14*2*64*8 = 14336 f16 = 28672 B
    float* Wp2 = (float*)((char*)d_ws + 28672);   // 224 f32

    repack_w<<<56, 256, 0, stream>>>(Whh1, Wih2, Wp, Wp2);
    lstm_main<<<512, 128, 0, stream>>>(X, Wp, Wp2, Wih1, bih1, bhh1, Whh2, bih2, bhh2, out);
}

// Round 8
// 825.662 us; speedup vs baseline: 1.0795x; 1.0795x over previous
//
#include <hip/hip_runtime.h>

#define TT 512

typedef _Float16 f16;
typedef _Float16 f16x4 __attribute__((ext_vector_type(4)));
typedef _Float16 f16x8 __attribute__((ext_vector_type(8)));
typedef float f32x4 __attribute__((ext_vector_type(4)));

__device__ __forceinline__ float fsig(float x){
    return __builtin_amdgcn_rcpf(1.f + __expf(-x));
}
__device__ __forceinline__ float ftanh_(float x){
    return 2.f * __builtin_amdgcn_rcpf(1.f + __expf(-2.f*x)) - 1.f;
}

// v_fma_mix_f32: dst.f32 += f16(src0 lo/hi) * f32(src1)
#define FMA_LO(accv, wd, hh) asm("v_fma_mix_f32 %0, %1, %2, %0 op_sel:[0,0,0] op_sel_hi:[1,0,0]" : "+v"(accv) : "v"(wd), "v"(hh))
#define FMA_HI(accv, wd, hh) asm("v_fma_mix_f32 %0, %1, %2, %0 op_sel:[1,0,0] op_sel_hi:[1,0,0]" : "+v"(accv) : "v"(wd), "v"(hh))

// Wp (f16): [13 m][2 kt][64 lane][8 b] A-fragments for mfma_f32_16x16x32_f16
//   row r = m*16 + (lane&15), r = 4*u+g unit-major; k = kt*32 + (lane>>4)*8 + b
//   col 0..50 = Whh1; col 51 = Wih1; col 52 = bih1+bhh1; col 53..63 = 0; rows u>=51 all 0
// Wp2 (f16): [52 u][4 g] = Wih2[g*51+u], zero-padded to 56
__global__ void repack_w(const float* __restrict__ Whh1, const float* __restrict__ Wih1,
                         const float* __restrict__ bih1, const float* __restrict__ bhh1,
                         const float* __restrict__ Wih2,
                         f16* __restrict__ Wp, f16* __restrict__ Wp2)
{
    int i = blockIdx.x*256 + threadIdx.x;
    if (i < 13*2*64*8) {
        int b    = i & 7;
        int lane = (i >> 3) & 63;
        int kt   = (i >> 9) & 1;
        int m    = i >> 10;
        int r = m*16 + (lane & 15);
        int u = r >> 2, g = r & 3;
        int k = kt*32 + (lane >> 4)*8 + b;
        float v = 0.f;
        if (u < 51) {
            int rt = g*51 + u;
            if      (k < 51)  v = Whh1[rt*51 + k];
            else if (k == 51) v = Wih1[rt];
            else if (k == 52) v = bih1[rt] + bhh1[rt];
        }
        Wp[i] = (f16)v;
    }
    if (i < 224) {
        int u = i >> 2, g = i & 3;
        Wp2[i] = (f16)((u < 51) ? Wih2[g*51 + u] : 0.f);
    }
}

__global__ __launch_bounds__(64, 1) void lstm_main(
    const float* __restrict__ X, const f16* __restrict__ Wp, const f16* __restrict__ Wp2,
    const float* __restrict__ Whh2, const float* __restrict__ bih2, const float* __restrict__ bhh2,
    float* __restrict__ out)
{
    // h buffer: [jl][u ^ (jl<<2)] f16, single buffer (wave-synchronous, DS in-order)
    __shared__ __align__(16) f16 HBs[16*64];   // 2048 B

    const int lane = threadIdx.x;
    const int q    = (lane >> 4) & 3;
    const int jl   = lane & 15;
    const int s    = jl << 2;
    const int bb   = blockIdx.x * 16;

    for (int i = lane; i < 512; i += 64) ((unsigned*)HBs)[i] = 0u;

    f16x8 A0[13], A1[13];
    uint2 w2p[13];
    #pragma unroll
    for (int j = 0; j < 13; ++j) {
        A0[j] = *(const f16x8*)(Wp + (j*2+0)*512 + lane*8);
        A1[j] = *(const f16x8*)(Wp + (j*2+1)*512 + lane*8);
        w2p[j] = *(const uint2*)(Wp2 + (j*4+q)*4);   // f16 gates (g0,g1|g2,g3)
    }
    float wh2[4], bs2[4];
    #pragma unroll
    for (int g = 0; g < 4; ++g) { wh2[g] = Whh2[g]; bs2[g] = bih2[g] + bhh2[g]; }

    float c1[13];
    #pragma unroll
    for (int j = 0; j < 13; ++j) c1[j] = 0.f;
    float c2 = 0.f, h2 = 0.f;

    const float* xp = X + (size_t)(bb + jl) * TT;

    // seed constant-1 slot (u=52) and x(0) slot (u=51); DS in-order vs later reads
    if (q == 0) HBs[jl*64 + (52 ^ s)] = (f16)1.f;
    if (q == 3) HBs[jl*64 + (51 ^ s)] = (f16)xp[0];

    const f16* rb = HBs + jl*64;
    const f32x4 zero4 = {0.f, 0.f, 0.f, 0.f};

    for (int t = 0; t < TT; ++t) {
        float xn = xp[(t+1 < TT) ? t+1 : t];

        f16x4 b0lo = *(const f16x4*)(rb + (((q*8)     ) ^ s));
        f16x4 b0hi = *(const f16x4*)(rb + (((q*8) | 4 ) ^ s));
        f16x4 b1lo = *(const f16x4*)(rb + (((q*8) + 32) ^ s));
        f16x4 b1hi = *(const f16x4*)(rb + (((q*8) + 36) ^ s));
        f16x8 B0 = __builtin_shufflevector(b0lo, b0hi, 0,1,2,3,4,5,6,7);
        f16x8 B1 = __builtin_shufflevector(b1lo, b1hi, 0,1,2,3,4,5,6,7);

        float p0 = 0.f, p1 = 0.f, p2 = 0.f, p3 = 0.f;
        #pragma unroll
        for (int j = 0; j < 13; ++j) {
            f32x4 a = __builtin_amdgcn_mfma_f32_16x16x32_f16(A0[j], B0, zero4, 0,0,0);
            a       = __builtin_amdgcn_mfma_f32_16x16x32_f16(A1[j], B1, a,     0,0,0);
            float ig = fsig(a[0]), fg = fsig(a[1]), gg = ftanh_(a[2]), og = fsig(a[3]);
            float c  = fg*c1[j] + ig*gg;
            c1[j] = c;
            float hv = og * ftanh_(c);
            int u = j*4 + q;
            if (j < 12 || q < 3)                    // u<51; only (j=12,q=3) is pad
                HBs[jl*64 + (u ^ s)] = (f16)hv;
            FMA_LO(p0, w2p[j].x, c); FMA_HI(p1, w2p[j].x, c);
            FMA_LO(p2, w2p[j].y, c); FMA_HI(p3, w2p[j].y, c);
        }

        if (q == 3) HBs[jl*64 + (51 ^ s)] = (f16)xn;   // x(t+1) into K-slot 51

        p0 += __shfl_xor(p0, 16); p0 += __shfl_xor(p0, 32);
        p1 += __shfl_xor(p1, 16); p1 += __shfl_xor(p1, 32);
        p2 += __shfl_xor(p2, 16); p2 += __shfl_xor(p2, 32);
        p3 += __shfl_xor(p3, 16); p3 += __shfl_xor(p3, 32);
        float g0 = p0 + bs2[0] + wh2[0]*h2;
        float g1 = p1 + bs2[1] + wh2[1]*h2;
        float g2 = p2 + bs2[2] + wh2[2]*h2;
        float g3 = p3 + bs2[3] + wh2[3]*h2;
        float i2 = fsig(g0), f2 = fsig(g1), gg2 = ftanh_(g2), o2 = fsig(g3);
        c2 = f2*c2 + i2*gg2;
        h2 = o2*ftanh_(c2);
    }

    // extra step: lstm1(input = c2) -> c1'; lstm2(input = c1') -> out = new c2
    if (q == 3) HBs[jl*64 + (51 ^ s)] = (f16)c2;
    {
        f16x4 b0lo = *(const f16x4*)(rb + (((q*8)     ) ^ s));
        f16x4 b0hi = *(const f16x4*)(rb + (((q*8) | 4 ) ^ s));
        f16x4 b1lo = *(const f16x4*)(rb + (((q*8) + 32) ^ s));
        f16x4 b1hi = *(const f16x4*)(rb + (((q*8) + 36) ^ s));
        f16x8 B0 = __builtin_shufflevector(b0lo, b0hi, 0,1,2,3,4,5,6,7);
        f16x8 B1 = __builtin_shufflevector(b1lo, b1hi, 0,1,2,3,4,5,6,7);

        float p0 = 0.f, p1 = 0.f, p2 = 0.f;
        #pragma unroll
        for (int j = 0; j < 13; ++j) {
            f32x4 a = __builtin_amdgcn_mfma_f32_16x16x32_f16(A0[j], B0, zero4, 0,0,0);
            a       = __builtin_amdgcn_mfma_f32_16x16x32_f16(A1[j], B1, a,     0,0,0);
            float ig = fsig(a[0]), fg = fsig(a[1]), gg = ftanh_(a[2]);
            float c  = fg*c1[j] + ig*gg;
            FMA_LO(p0, w2p[j].x, c); FMA_HI(p1, w2p[j].x, c);
            FMA_LO(p2, w2p[j].y, c);
        }
        p0 += __shfl_xor(p0, 16); p0 += __shfl_xor(p0, 32);
        p1 += __shfl_xor(p1, 16); p1 += __shfl_xor(p1, 32);
        p2 += __shfl_xor(p2, 16); p2 += __shfl_xor(p2, 32);
        float g0 = p0 + bs2[0] + wh2[0]*h2;
        float g1 = p1 + bs2[1] + wh2[1]*h2;
        float g2 = p2 + bs2[2] + wh2[2]*h2;
        float i2 = fsig(g0), f2 = fsig(g1), gg2 = ftanh_(g2);
        float c2n = f2*c2 + i2*gg2;
        if (lane < 16) out[bb + jl] = c2n;
    }
}

extern "C" void kernel_launch(void* const* d_in, const int* in_sizes, int n_in,
                              void* d_out, int out_size, void* d_ws, size_t ws_size,
                              hipStream_t stream) {
    const float* X    = (const float*)d_in[0];
    const float* Wih1 = (const float*)d_in[1];
    const float* Whh1 = (const float*)d_in[2];
    const float* bih1 = (const float*)d_in[3];
    const float* bhh1 = (const float*)d_in[4];
    const float* Wih2 = (const float*)d_in[5];
    const float* Whh2 = (const float*)d_in[6];
    const float* bih2 = (const float*)d_in[7];
    const float* bhh2 = (const float*)d_in[8];
    float* out = (float*)d_out;

    f16* Wp  = (f16*)d_ws;                      // 13312 f16 = 26624 B
    f16* Wp2 = (f16*)((char*)d_ws + 26624);     // 224 f16

    repack_w<<<52, 256, 0, stream>>>(Whh1, Wih1, bih1, bhh1, Wih2, Wp, Wp2);
    lstm_main<<<512, 64, 0, stream>>>(X, Wp, Wp2, Whh2, bih2, bhh2, out);
}

// Round 10
// 451.160 us; speedup vs baseline: 1.9757x; 1.8301x over previous
//
#include <hip/hip_runtime.h>

#define TT 512

typedef _Float16 f16;
typedef _Float16 f16x4 __attribute__((ext_vector_type(4)));
typedef _Float16 f16x8 __attribute__((ext_vector_type(8)));
typedef float f32x4 __attribute__((ext_vector_type(4)));

__device__ __forceinline__ float fsig(float x){
    return __builtin_amdgcn_rcpf(1.f + __expf(-x));
}
__device__ __forceinline__ float ftanh_(float x){
    return 2.f * __builtin_amdgcn_rcpf(1.f + __expf(-2.f*x)) - 1.f;
}

// v_fma_mix_f32: dst.f32 += f16(src0 lo/hi) * f32(src1)
#define FMA_LO(accv, wd, hh) asm("v_fma_mix_f32 %0, %1, %2, %0 op_sel:[0,0,0] op_sel_hi:[1,0,0]" : "+v"(accv) : "v"(wd), "v"(hh))
#define FMA_HI(accv, wd, hh) asm("v_fma_mix_f32 %0, %1, %2, %0 op_sel:[1,0,0] op_sel_hi:[1,0,0]" : "+v"(accv) : "v"(wd), "v"(hh))

// Wp (f16): [13 m][2 kt][64 lane][8 b] A-fragments for mfma_f32_16x16x32_f16
//   row r = m*16 + (lane&15), r = 4*u+g unit-major; k = kt*32 + (lane>>4)*8 + b
//   col 0..50 = Whh1; col 51 = Wih1; col 52 = bih1+bhh1; col 53..63 = 0; rows u>=51 all 0
// Wp2 (f16): [56 u][4 g] = Wih2[g*51+u], zero-padded
__global__ void repack_w(const float* __restrict__ Whh1, const float* __restrict__ Wih1,
                         const float* __restrict__ bih1, const float* __restrict__ bhh1,
                         const float* __restrict__ Wih2,
                         f16* __restrict__ Wp, f16* __restrict__ Wp2)
{
    int i = blockIdx.x*256 + threadIdx.x;
    if (i < 13*2*64*8) {
        int b    = i & 7;
        int lane = (i >> 3) & 63;
        int kt   = (i >> 9) & 1;
        int m    = i >> 10;
        int r = m*16 + (lane & 15);
        int u = r >> 2, g = r & 3;
        int k = kt*32 + (lane >> 4)*8 + b;
        float v = 0.f;
        if (u < 51) {
            int rt = g*51 + u;
            if      (k < 51)  v = Whh1[rt*51 + k];
            else if (k == 51) v = Wih1[rt];
            else if (k == 52) v = bih1[rt] + bhh1[rt];
        }
        Wp[i] = (f16)v;
    }
    if (i < 224) {
        int u = i >> 2, g = i & 3;
        Wp2[i] = (f16)((u < 51) ? Wih2[g*51 + u] : 0.f);
    }
}

__global__ __launch_bounds__(256, 2) void lstm_main(
    const float* __restrict__ X, const f16* __restrict__ Wp, const f16* __restrict__ Wp2,
    const float* __restrict__ Whh2, const float* __restrict__ bih2, const float* __restrict__ bhh2,
    float* __restrict__ out)
{
    // Single-buffer state. Discipline: READ phase | barrier A | WRITE phase | barrier B.
    // HB:  [jl][64] f16, elem index swizzled (u ^ (jl<<2))     2048 B
    // PBL: [wave][jl] f32x4 layer-2 gate partials              1024 B
    __shared__ __align__(16) f16   HB[1024];
    __shared__ __align__(16) float PBL[4][16][4];

    const int tid  = threadIdx.x;
    const int w    = tid >> 6;         // wave 0..3
    const int lane = tid & 63;
    const int q    = (lane >> 4) & 3;
    const int jl   = lane & 15;
    const int s    = jl << 2;
    const int bb   = blockIdx.x * 16;

    for (int i = tid; i < 512; i += 256) ((unsigned*)HB)[i] = 0u;
    {   // zero PBL (256 dwords)
        int i = tid;
        if (i < 256) ((unsigned*)PBL)[i] = 0u;
    }
    __syncthreads();
    if (w == 0 && lane < 16) {         // seed bias slot (1.0) and x(0)
        int ss = lane << 2;
        HB[lane*64 + (52 ^ ss)] = (f16)1.f;
        HB[lane*64 + (51 ^ ss)] = (f16)X[(size_t)(bb + lane)*TT];
    }

    const bool has4 = (w == 1);        // wave 1 owns tile 12
    const int tiles[4] = {w, 4+w, 8+w, 12};
    f16x8 A0[4], A1[4];
    uint2 w2p[4];
    #pragma unroll
    for (int k = 0; k < 4; ++k) {
        int m = tiles[k];
        A0[k]  = *(const f16x8*)(Wp + (m*2+0)*512 + lane*8);
        A1[k]  = *(const f16x8*)(Wp + (m*2+1)*512 + lane*8);
        w2p[k] = *(const uint2*)(Wp2 + (m*4+q)*4);
    }
    float wh2[4], bs2[4];
    #pragma unroll
    for (int g = 0; g < 4; ++g) { wh2[g] = Whh2[g]; bs2[g] = bih2[g] + bhh2[g]; }

    float c1[4] = {0.f, 0.f, 0.f, 0.f};
    float c2 = 0.f, h2 = 0.f;          // live in wave 3 (all lanes redundant)
    const f32x4 zero4 = {0.f, 0.f, 0.f, 0.f};

    const float* xp = X + (size_t)(bb + jl) * TT;
    __syncthreads();

    for (int t = 0; t < TT; ++t) {
        // ---------- READ phase ----------
        const f16* rb = HB + jl*64;
        f16x4 b0lo = *(const f16x4*)(rb + (((q*8)     ) ^ s));
        f16x4 b0hi = *(const f16x4*)(rb + (((q*8) | 4 ) ^ s));
        f16x4 b1lo = *(const f16x4*)(rb + (((q*8) + 32) ^ s));
        f16x4 b1hi = *(const f16x4*)(rb + (((q*8) + 36) ^ s));
        f16x8 B0 = __builtin_shufflevector(b0lo, b0hi, 0,1,2,3,4,5,6,7);
        f16x8 B1 = __builtin_shufflevector(b1lo, b1hi, 0,1,2,3,4,5,6,7);

        f32x4 S0, S1, S2, S3;
        if (w == 3) {                   // layer-2 partials of step t-1 (zeros at t=0)
            S0 = *(const f32x4*)&PBL[0][jl][0];
            S1 = *(const f32x4*)&PBL[1][jl][0];
            S2 = *(const f32x4*)&PBL[2][jl][0];
            S3 = *(const f32x4*)&PBL[3][jl][0];
        }
        float xn = xp[(t+1 < TT) ? t+1 : t];

        __syncthreads();                // A: all reads complete

        // ---------- WRITE phase ----------
        if (w == 3 && t > 0) {          // layer-2 LSTM for step t-1 (register-only)
            f32x4 S = S0 + S1 + S2 + S3;
            float g0 = S[0] + bs2[0] + wh2[0]*h2;
            float g1 = S[1] + bs2[1] + wh2[1]*h2;
            float g2 = S[2] + bs2[2] + wh2[2]*h2;
            float g3 = S[3] + bs2[3] + wh2[3]*h2;
            float i2 = fsig(g0), f2 = fsig(g1), gg2 = ftanh_(g2), o2 = fsig(g3);
            c2 = f2*c2 + i2*gg2;
            h2 = o2*ftanh_(c2);
        }

        float p0 = 0.f, p1 = 0.f, p2 = 0.f, p3 = 0.f;
        #pragma unroll
        for (int k = 0; k < 4; ++k) {
            if (k < 3 || has4) {
                f32x4 a = __builtin_amdgcn_mfma_f32_16x16x32_f16(A0[k], B0, zero4, 0,0,0);
                a       = __builtin_amdgcn_mfma_f32_16x16x32_f16(A1[k], B1, a,     0,0,0);
                float ig = fsig(a[0]), fg = fsig(a[1]), gg = ftanh_(a[2]), og = fsig(a[3]);
                float c  = fg*c1[k] + ig*gg;
                c1[k] = c;
                int u = tiles[k]*4 + q;
                if (k < 3 || q < 3)     // u<51 (only tile12/q3 is the pad unit)
                    HB[jl*64 + (u ^ s)] = (f16)(og * ftanh_(c));
                FMA_LO(p0, w2p[k].x, c); FMA_HI(p1, w2p[k].x, c);
                FMA_LO(p2, w2p[k].y, c); FMA_HI(p3, w2p[k].y, c);
            }
        }
        if (w == 0 && q == 3)
            HB[jl*64 + (51 ^ s)] = (f16)xn;    // x(t+1) -> K-slot 51

        p0 += __shfl_xor(p0, 16); p0 += __shfl_xor(p0, 32);
        p1 += __shfl_xor(p1, 16); p1 += __shfl_xor(p1, 32);
        p2 += __shfl_xor(p2, 16); p2 += __shfl_xor(p2, 32);
        p3 += __shfl_xor(p3, 16); p3 += __shfl_xor(p3, 32);
        if (lane < 16) {
            f32x4 pv = {p0, p1, p2, p3};
            *(f32x4*)&PBL[w][jl][0] = pv;
        }
        __syncthreads();                // B: all writes sealed
    }
    // HB holds h(512), slot52=1.0; PBL holds step-511 partials; c2/h2 through step 510.

    // wave 3: layer-2 for step 511 (reads PBL sealed by B(511)), publish c2 into slot 51
    if (w == 3) {
        f32x4 S = *(const f32x4*)&PBL[0][jl][0];
        S += *(const f32x4*)&PBL[1][jl][0];
        S += *(const f32x4*)&PBL[2][jl][0];
        S += *(const f32x4*)&PBL[3][jl][0];
        float g0 = S[0] + bs2[0] + wh2[0]*h2;
        float g1 = S[1] + bs2[1] + wh2[1]*h2;
        float g2 = S[2] + bs2[2] + wh2[2]*h2;
        float g3 = S[3] + bs2[3] + wh2[3]*h2;
        float i2 = fsig(g0), f2 = fsig(g1), gg2 = ftanh_(g2), o2 = fsig(g3);
        c2 = f2*c2 + i2*gg2;
        h2 = o2*ftanh_(c2);
        if (lane < 16) HB[jl*64 + (51 ^ s)] = (f16)c2;
    }
    __syncthreads();                    // C

    // extra step: lstm1(input = c2) -> c1'; partials -> PBL
    {
        const f16* rb = HB + jl*64;
        f16x4 b0lo = *(const f16x4*)(rb + (((q*8)     ) ^ s));
        f16x4 b0hi = *(const f16x4*)(rb + (((q*8) | 4 ) ^ s));
        f16x4 b1lo = *(const f16x4*)(rb + (((q*8) + 32) ^ s));
        f16x4 b1hi = *(const f16x4*)(rb + (((q*8) + 36) ^ s));
        f16x8 B0 = __builtin_shufflevector(b0lo, b0hi, 0,1,2,3,4,5,6,7);
        f16x8 B1 = __builtin_shufflevector(b1lo, b1hi, 0,1,2,3,4,5,6,7);

        float p0 = 0.f, p1 = 0.f, p2 = 0.f, p3 = 0.f;
        #pragma unroll
        for (int k = 0; k < 4; ++k) {
            if (k < 3 || has4) {
                f32x4 a = __builtin_amdgcn_mfma_f32_16x16x32_f16(A0[k], B0, zero4, 0,0,0);
                a       = __builtin_amdgcn_mfma_f32_16x16x32_f16(A1[k], B1, a,     0,0,0);
                float ig = fsig(a[0]), fg = fsig(a[1]), gg = ftanh_(a[2]);
                float c  = fg*c1[k] + ig*gg;
                FMA_LO(p0, w2p[k].x, c); FMA_HI(p1, w2p[k].x, c);
                FMA_LO(p2, w2p[k].y, c); FMA_HI(p3, w2p[k].y, c);
            }
        }
        p0 += __shfl_xor(p0, 16); p0 += __shfl_xor(p0, 32);
        p1 += __shfl_xor(p1, 16); p1 += __shfl_xor(p1, 32);
        p2 += __shfl_xor(p2, 16); p2 += __shfl_xor(p2, 32);
        p3 += __shfl_xor(p3, 16); p3 += __shfl_xor(p3, 32);
        if (lane < 16) {
            f32x4 pv = {p0, p1, p2, p3};
            *(f32x4*)&PBL[w][jl][0] = pv;
        }
    }
    __syncthreads();                    // D

    // final: lstm2 gates on c1' -> out = new c2
    if (w == 3) {
        f32x4 S = *(const f32x4*)&PBL[0][jl][0];
        S += *(const f32x4*)&PBL[1][jl][0];
        S += *(const f32x4*)&PBL[2][jl][0];
        S += *(const f32x4*)&PBL[3][jl][0];
        float g0 = S[0] + bs2[0] + wh2[0]*h2;
        float g1 = S[1] + bs2[1] + wh2[1]*h2;
        float g2 = S[2] + bs2[2] + wh2[2]*h2;
        float i2 = fsig(g0), f2 = fsig(g1), gg2 = ftanh_(g2);
        float c2n = f2*c2 + i2*gg2;
        if (lane < 16) out[bb + jl] = c2n;
    }
}

extern "C" void kernel_launch(void* const* d_in, const int* in_sizes, int n_in,
                              void* d_out, int out_size, void* d_ws, size_t ws_size,
                              hipStream_t stream) {
    const float* X    = (const float*)d_in[0];
    const float* Wih1 = (const float*)d_in[1];
    const float* Whh1 = (const float*)d_in[2];
    const float* bih1 = (const float*)d_in[3];
    const float* bhh1 = (const float*)d_in[4];
    const float* Wih2 = (const float*)d_in[5];
    const float* Whh2 = (const float*)d_in[6];
    const float* bih2 = (const float*)d_in[7];
    const float* bhh2 = (const float*)d_in[8];
    float* out = (float*)d_out;

    f16* Wp  = (f16*)d_ws;                      // 13312 f16 = 26624 B
    f16* Wp2 = (f16*)((char*)d_ws + 26624);     // 224 f16

    repack_w<<<52, 256, 0, stream>>>(Whh1, Wih1, bih1, bhh1, Wih2, Wp, Wp2);
    lstm_main<<<512, 256, 0, stream>>>(X, Wp, Wp2, Whh2, bih2, bhh2, out);
}